// Round 11
// baseline (373.172 us; speedup 1.0000x reference)
//
#include <hip/hip_runtime.h>
#include <hip/hip_bf16.h>

typedef __attribute__((ext_vector_type(8))) short bf16x8;
typedef __attribute__((ext_vector_type(4))) short s16x4;
typedef __attribute__((ext_vector_type(4))) float f32x4;

#define DIM    1024
#define TOKENS 4096
#define NHEAD  16
#define HD     64
#define EXP_N  7168
#define CON_N  2048
#define HF     5120

// workspace arena (bytes). NOTE liveness: wc_bf (WC_OFF=0) ALIASES
// wexp_bf + xn, so the Wc f2bf conversion MUST launch after gemm1.
#define WEXP_OFF 0u          // 7168*1024*2 = 14,680,064
#define XN_OFF   14680064u   // 4096*1024*2 =  8,388,608
#define WC_OFF   0u          // 2048*5120*2 = 20,971,520 (reuses Wexp+xn after gemm1)
#define Q_OFF    23068672u   // 8,388,608
#define K_OFF    31457280u   // 8,388,608
#define V_OFF    39845888u   // 8,388,608
#define H_OFF    48234496u   // 4096*5120*2 = 41,943,040
#define PERM_OFF 90177536u   // 4096*4
#define DSRT_OFF 90193920u   // 4096*4
#define TMAX_OFF 90210304u   // 64*4
#define OUT2_OFF 23068672u   // 4096*2048*2 = 16,777,216 (reuses q+k after attn)

__device__ __forceinline__ short f2bf(float f) {
  union { __hip_bfloat16 h; short s; } u;
  u.h = __float2bfloat16(f);
  return u.s;
}
__device__ __forceinline__ float bf2f(short s) {
  unsigned int u = ((unsigned int)(unsigned short)s) << 16;
  return __builtin_bit_cast(float, u);
}

// async global -> LDS, 16 bytes per lane. LDS dest is wave-uniform base
// (HW writes lane i at base + i*16); global src address is PER-LANE.
__device__ __forceinline__ void gload16(const void* g, void* l) {
  __builtin_amdgcn_global_load_lds((const __attribute__((address_space(1))) void*)g,
                                   (__attribute__((address_space(3))) void*)l,
                                   16, 0, 0);
}

__device__ __forceinline__ void block_reduce_2(float& a, float& b) {
  #pragma unroll
  for (int off = 32; off > 0; off >>= 1) {
    a += __shfl_down(a, off);
    b += __shfl_down(b, off);
  }
  __shared__ float red[2][4];
  int wid = threadIdx.x >> 6, lane = threadIdx.x & 63;
  if (lane == 0) { red[0][wid] = a; red[1][wid] = b; }
  __syncthreads();
  a = red[0][0] + red[0][1] + red[0][2] + red[0][3];
  b = red[1][0] + red[1][1] + red[1][2] + red[1][3];
}

// ---------------- stable counting sort of tokens by expert id ----------------
// tile_demax[t] = max d_e over sorted rows [t*64, t*64+64)  (64 tiles of 64)
__global__ __launch_bounds__(256) void sort_kernel(const int* __restrict__ emask,
                                                   int* __restrict__ perm,
                                                   int* __restrict__ de_sorted,
                                                   int* __restrict__ tile_demax) {
  __shared__ int cnt[4][256];
  __shared__ int boff[4];
  __shared__ int lm[256];
  const int t = threadIdx.x;
  const int lane = t & 63, w = t >> 6;
  int msk[16];
  int lc4[4] = {0, 0, 0, 0};
  #pragma unroll
  for (int j = 0; j < 16; ++j) { msk[j] = emask[t * 16 + j]; lc4[msk[j]]++; }
  #pragma unroll
  for (int b = 0; b < 4; ++b) cnt[b][t] = lc4[b];
  __syncthreads();
  {  // wave w: exclusive scan of bucket w over 256 thread-counts (4 per lane)
    int v0 = cnt[w][lane * 4], v1 = cnt[w][lane * 4 + 1];
    int v2 = cnt[w][lane * 4 + 2], v3 = cnt[w][lane * 4 + 3];
    int s = v0 + v1 + v2 + v3;
    int inc = s;
    #pragma unroll
    for (int off = 1; off < 64; off <<= 1) {
      int n = __shfl_up(inc, off);
      if (lane >= off) inc += n;
    }
    int ex = inc - s;
    cnt[w][lane * 4]     = ex;
    cnt[w][lane * 4 + 1] = ex + v0;
    cnt[w][lane * 4 + 2] = ex + v0 + v1;
    cnt[w][lane * 4 + 3] = ex + v0 + v1 + v2;
    if (lane == 63) boff[w] = inc;  // bucket total (temp)
  }
  __syncthreads();
  if (t == 0) {
    int t0 = boff[0], t1 = boff[1], t2 = boff[2];
    boff[0] = 0; boff[1] = t0; boff[2] = t0 + t1; boff[3] = t0 + t1 + t2;
  }
  __syncthreads();
  int c4[4] = {0, 0, 0, 0};
  #pragma unroll
  for (int j = 0; j < 16; ++j) {
    int b = msk[j];
    int pos = boff[b] + cnt[b][t] + c4[b]++;
    perm[pos] = t * 16 + j;
    de_sorted[pos] = DIM >> (3 - b);
  }
  __syncthreads();
  int mx = 0;
  #pragma unroll
  for (int j = 0; j < 16; ++j) mx = max(mx, de_sorted[t * 16 + j]);
  lm[t] = mx;
  __syncthreads();
  if (t < 64) {
    int m2 = 0;
    #pragma unroll
    for (int j = 0; j < 4; ++j) m2 = max(m2, lm[t * 4 + j]);
    tile_demax[t] = m2;
  }
}

// ---------------- fp32 -> bf16 weight conversion ----------------
__global__ __launch_bounds__(256) void f2bf_kernel(const float* __restrict__ in,
                                                   short* __restrict__ outp, int n4) {
  for (int i = blockIdx.x * blockDim.x + threadIdx.x; i < n4; i += gridDim.x * blockDim.x) {
    f32x4 xv = *(const f32x4*)(&in[(size_t)i * 4]);
    s16x4 o = { f2bf(xv[0]), f2bf(xv[1]), f2bf(xv[2]), f2bf(xv[3]) };
    *(s16x4*)(&outp[(size_t)i * 4]) = o;
  }
}

// ---------------- LN1 + fmask -> xn (bf16) ----------------
__global__ __launch_bounds__(256) void ln1_kernel(const float* __restrict__ x,
                                                  const int* __restrict__ emask,
                                                  const float* __restrict__ g,
                                                  const float* __restrict__ bb,
                                                  short* __restrict__ xn) {
  int m = blockIdx.x, t = threadIdx.x;
  const float* row = x + (size_t)m * DIM;
  f32x4 xv = *(const f32x4*)(&row[t * 4]);
  float s  = xv[0] + xv[1] + xv[2] + xv[3];
  float ss = xv[0] * xv[0] + xv[1] * xv[1] + xv[2] * xv[2] + xv[3] * xv[3];
  block_reduce_2(s, ss);
  float mean = s * (1.0f / DIM);
  float var  = ss * (1.0f / DIM) - mean * mean;
  float inv  = rsqrtf(var + 1e-5f);
  int de = DIM >> (3 - emask[m]);
  s16x4 o;
  #pragma unroll
  for (int jj = 0; jj < 4; ++jj) {
    int c = t * 4 + jj;
    float v = (c < de) ? ((xv[jj] - mean) * inv * g[c] + bb[c]) : 0.f;
    o[jj] = f2bf(v);
  }
  *(s16x4*)(&xn[(size_t)m * DIM + t * 4]) = o;
}

// ---------------- shared 64x128xK bf16 GEMM core, 256 threads / 4 waves ----
// M-tile 64 (was 128): 4-wave blocks, 36 KB LDS -> 4 blocks/CU residency.
// Independent co-resident blocks hide each other's vmcnt/barrier stalls
// (the m114 mechanism the 1-block/CU gemm2 could not use).
// Wave wid owns all 64 rows x cols [wid*32, +32) -> acc[4][2],
// 8 MFMA + 6 ds_read_b128 per step.
// Staging per wave per stage: A-chunk wid + B-chunks 2*wid, 2*wid+1
// (chunk = 16 rows x 32 cols = 1024B, HW base + lane*16 rule).
// T2 swizzle (rule #21): linear LDS dest + pre-swizzled global SOURCE unit
// (l&3)^((l>>3)&3) + swizzled READ unit lg^((lc>>1)&3)  [conflict-free,
// verified round 10: SQ_LDS_BANK_CONFLICT -> 0].
// Pipeline: 3-buffer prefetch-distance-2, counted vmcnt 6/3/0 (T3+T4),
// setprio around MFMA (T5). K % 64 == 0, K >= 128.
#define ABUF 2048  // shorts per A LDS buffer (64*32)
#define BBUF 4096  // shorts per B LDS buffer (128*32)

#define STAGE(Asb, Bsb, kk)                                   \
  do {                                                        \
    gload16(Apw + (kk), (Asb) + wid * 512);                   \
    gload16(Bpw0 + (kk), (Bsb) + (2 * wid) * 512);            \
    gload16(Bpw1 + (kk), (Bsb) + (2 * wid + 1) * 512);        \
  } while (0)

#define COMPUTE(Asb, Bsb)                                                     \
  do {                                                                        \
    bf16x8 af[4], bfr[2];                                                     \
    _Pragma("unroll")                                                         \
    for (int i = 0; i < 4; ++i)                                               \
      af[i] = *(const bf16x8*)(&(Asb)[(i * 16 + lc) * 32 + lgs]);             \
    _Pragma("unroll")                                                         \
    for (int j = 0; j < 2; ++j)                                               \
      bfr[j] = *(const bf16x8*)(&(Bsb)[(wid * 32 + j * 16 + lc) * 32 + lgs]); \
    __builtin_amdgcn_s_setprio(1);                                            \
    _Pragma("unroll")                                                         \
    for (int i = 0; i < 4; ++i)                                               \
      _Pragma("unroll")                                                       \
      for (int j = 0; j < 2; ++j)                                             \
        acc[i][j] = __builtin_amdgcn_mfma_f32_16x16x32_bf16(af[i], bfr[j],    \
                                                            acc[i][j], 0, 0, 0);\
    __builtin_amdgcn_s_setprio(0);                                            \
  } while (0)

#define VMCNT(n) asm volatile("s_waitcnt vmcnt(" #n ")" ::: "memory")

__device__ __forceinline__ void gemm_core_64(const short* __restrict__ A,
                                             const short* __restrict__ B,
                                             int lda, int ldb, int K,
                                             int m0, int n0,
                                             const int* __restrict__ aperm,
                                             short* AS, short* BS,
                                             f32x4 acc[4][2]) {
  const int tid = threadIdx.x;
  const int lane = tid & 63;
  const int wid = tid >> 6;           // 0..3
  const int lg = lane >> 4, lc = lane & 15;
  const int lgs = (lg ^ ((lc >> 1) & 3)) * 8;   // swizzled read unit (shorts)
  const int r4 = lane >> 2;        // 0..15
  const int c8 = ((lane & 3) ^ ((lane >> 3) & 3)) * 8;  // swizzled src unit
  int ra = m0 + wid * 16 + r4;
  if (aperm) ra = aperm[ra];
  const short* Apw  = A + (size_t)ra * lda + c8;
  const short* Bpw0 = B + (size_t)(n0 + (2 * wid) * 16 + r4) * ldb + c8;
  const short* Bpw1 = B + (size_t)(n0 + (2 * wid + 1) * 16 + r4) * ldb + c8;

  const int nt = K >> 5;           // 32-K steps, nt >= 4
  STAGE(AS + 0 * ABUF, BS + 0 * BBUF, 0);
  STAGE(AS + 1 * ABUF, BS + 1 * BBUF, 32);
  STAGE(AS + 2 * ABUF, BS + 2 * BBUF, 64);
  int cur = 0;
  for (int t = 0; t < nt - 2; ++t) {
    short* Ac = AS + cur * ABUF;
    short* Bc = BS + cur * BBUF;
    VMCNT(6);
    __builtin_amdgcn_s_barrier();
    COMPUTE(Ac, Bc);
    __builtin_amdgcn_s_barrier();
    if (t < nt - 3) STAGE(Ac, Bc, (t + 3) * 32);
    cur = (cur == 2) ? 0 : cur + 1;
  }
  {
    short* Ac = AS + cur * ABUF;
    short* Bc = BS + cur * BBUF;
    VMCNT(3);
    __builtin_amdgcn_s_barrier();
    COMPUTE(Ac, Bc);
    cur = (cur == 2) ? 0 : cur + 1;
  }
  {
    short* Ac = AS + cur * ABUF;
    short* Bc = BS + cur * BBUF;
    VMCNT(0);
    __builtin_amdgcn_s_barrier();
    COMPUTE(Ac, Bc);
  }
}

// XCD-aware bijective block swizzle, COLUMN-MAJOR decode: each XCD's
// contiguous tile chunk spans a bx (output-column) range while cycling
// through ALL by (token-tile) values -> per-XCD work stays balanced even
// though K varies with by (expert-sorted rows). grid count must be %8==0.
__device__ __forceinline__ void xcd_swizzle_cm(int& bx, int& by) {
  int nwg = gridDim.x * gridDim.y;
  int bid = blockIdx.y * gridDim.x + blockIdx.x;
  int cpx = nwg >> 3;
  int swz = (bid & 7) * cpx + (bid >> 3);
  by = swz % gridDim.y;
  bx = swz / gridDim.y;
}

// ---------------- GEMM1: y = xn[perm] @ Wexp^T, K limited to tile d_e max ----
__global__ __launch_bounds__(256) void gemm1_kernel(const short* __restrict__ xn,
                                                    const short* __restrict__ Wexp,
                                                    const float* __restrict__ mlpb,
                                                    const int* __restrict__ perm,
                                                    const int* __restrict__ tmax,
                                                    short* __restrict__ qbuf,
                                                    short* __restrict__ kbuf,
                                                    short* __restrict__ vbuf,
                                                    short* __restrict__ hbuf) {
  __shared__ __align__(16) short AS[3 * ABUF];
  __shared__ __align__(16) short BS[3 * BBUF];
  f32x4 acc[4][2];
  f32x4 z = {0.f, 0.f, 0.f, 0.f};
  #pragma unroll
  for (int i = 0; i < 4; ++i)
    #pragma unroll
    for (int j = 0; j < 2; ++j) acc[i][j] = z;
  int bx, by;
  xcd_swizzle_cm(bx, by);
  int n0 = bx * 128;
  int m0 = by * 64;
  int kmax = tmax[by];
  gemm_core_64(xn, Wexp, DIM, DIM, kmax, m0, n0, perm, AS, BS, acc);
  const int tid = threadIdx.x, lane = tid & 63, wid = tid >> 6;
  const int lg = lane >> 4, lc = lane & 15;
  int toks[4][4];
  #pragma unroll
  for (int i = 0; i < 4; ++i)
    #pragma unroll
    for (int r = 0; r < 4; ++r)
      toks[i][r] = perm[m0 + i * 16 + lg * 4 + r];
  #pragma unroll
  for (int i = 0; i < 4; ++i) {
    #pragma unroll
    for (int j = 0; j < 2; ++j) {
      int e = n0 + wid * 32 + j * 16 + lc;
      #pragma unroll
      for (int r = 0; r < 4; ++r) {
        int m = toks[i][r];
        float val = acc[i][j][r];
        if (e < DIM) {
          qbuf[(size_t)m * DIM + e] = f2bf((val + mlpb[e]) * 0.125f);
        } else if (e < 2 * DIM) {
          kbuf[(size_t)m * DIM + (e - DIM)] = f2bf(val + mlpb[e]);
        } else if (e < 3 * DIM) {
          vbuf[(size_t)m * DIM + (e - 2 * DIM)] = f2bf(val + mlpb[e]);
        } else {
          int jj = e - 3 * DIM;
          float xx = val + mlpb[jj] + (e < 4 * DIM ? mlpb[e] : 0.f);
          float ge = 0.5f * xx * (1.f + erff(xx * 0.70710678118654752f));
          hbuf[(size_t)m * HF + DIM + jj] = f2bf(ge);
        }
      }
    }
  }
}

// ---------------- LN2 in place on k/v (bf16 rows) ----------------
__global__ __launch_bounds__(256) void ln2_kernel(short* __restrict__ kbuf,
                                                  short* __restrict__ vbuf,
                                                  const float* __restrict__ g,
                                                  const float* __restrict__ bb) {
  int rr = blockIdx.x;
  int m = rr >> 1;
  short* row = ((rr & 1) ? vbuf : kbuf) + (size_t)m * DIM;
  int t = threadIdx.x;
  s16x4 iv = *(const s16x4*)(&row[t * 4]);
  float f[4];
  #pragma unroll
  for (int jj = 0; jj < 4; ++jj) f[jj] = bf2f(iv[jj]);
  float s = f[0] + f[1] + f[2] + f[3];
  float ss = f[0] * f[0] + f[1] * f[1] + f[2] * f[2] + f[3] * f[3];
  block_reduce_2(s, ss);
  float mean = s * (1.0f / DIM);
  float var  = ss * (1.0f / DIM) - mean * mean;
  float inv  = rsqrtf(var + 1e-5f);
  s16x4 o;
  #pragma unroll
  for (int jj = 0; jj < 4; ++jj) {
    int c = t * 4 + jj;
    o[jj] = f2bf((f[jj] - mean) * inv * g[c] + bb[c]);
  }
  *(s16x4*)(&row[t * 4]) = o;
}

// ---------------- flash attention: per (b,h) 64 q-rows per block ----------------
__global__ __launch_bounds__(256) void attn_kernel(const short* __restrict__ q,
                                                   const short* __restrict__ k,
                                                   const short* __restrict__ v,
                                                   short* __restrict__ hbuf) {
  __shared__ __align__(16) short Kt[64 * 72];
  __shared__ __align__(16) short Vt[64 * 72];
  __shared__ __align__(16) short Pl[4][16 * 72];
  const int bh = blockIdx.x;
  const int b = bh >> 4, hh = bh & 15;
  const int qt = blockIdx.y;
  const int tid = threadIdx.x, w = tid >> 6, lane = tid & 63;
  const int lg = lane >> 4, lc = lane & 15;

  bf16x8 qa0, qa1;
  {
    const short* qbase = q + ((size_t)(b * 1024 + qt * 64 + w * 16 + lc)) * DIM + hh * HD;
    qa0 = *(const bf16x8*)(qbase + lg * 8);
    qa1 = *(const bf16x8*)(qbase + 32 + lg * 8);
  }
  f32x4 po[4];
  f32x4 z = {0.f, 0.f, 0.f, 0.f};
  #pragma unroll
  for (int d = 0; d < 4; ++d) po[d] = z;
  float mrun[4] = {-INFINITY, -INFINITY, -INFINITY, -INFINITY};
  float lsum[4] = {0.f, 0.f, 0.f, 0.f};

  for (int kt = 0; kt < 16; ++kt) {
    __syncthreads();
    const int kc0 = kt * 64;
    #pragma unroll
    for (int it = 0; it < 2; ++it) {
      int row = (tid >> 3) + it * 32;
      int c8 = (tid & 7) * 8;
      size_t gb = ((size_t)(b * 1024 + kc0 + row)) * DIM + hh * HD + c8;
      *(bf16x8*)(&Kt[row * 72 + c8]) = *(const bf16x8*)(&k[gb]);
      bf16x8 vv = *(const bf16x8*)(&v[gb]);
      #pragma unroll
      for (int jj = 0; jj < 8; ++jj) Vt[(c8 + jj) * 72 + row] = vv[jj];
    }
    __syncthreads();
    f32x4 sacc[4];
    #pragma unroll
    for (int cb = 0; cb < 4; ++cb) {
      bf16x8 kb0 = *(const bf16x8*)(&Kt[(cb * 16 + lc) * 72 + lg * 8]);
      bf16x8 kb1 = *(const bf16x8*)(&Kt[(cb * 16 + lc) * 72 + 32 + lg * 8]);
      f32x4 t0 = __builtin_amdgcn_mfma_f32_16x16x32_bf16(qa0, kb0, z, 0, 0, 0);
      sacc[cb] = __builtin_amdgcn_mfma_f32_16x16x32_bf16(qa1, kb1, t0, 0, 0, 0);
    }
    #pragma unroll
    for (int r = 0; r < 4; ++r) {
      float mx = fmaxf(fmaxf(sacc[0][r], sacc[1][r]), fmaxf(sacc[2][r], sacc[3][r]));
      #pragma unroll
      for (int off = 1; off < 16; off <<= 1) mx = fmaxf(mx, __shfl_xor(mx, off));
      float mnew = fmaxf(mrun[r], mx);
      float al = __expf(mrun[r] - mnew);
      mrun[r] = mnew;
      float ps = 0.f;
      #pragma unroll
      for (int cb = 0; cb < 4; ++cb) {
        float p = __expf(sacc[cb][r] - mnew);
        sacc[cb][r] = p;
        ps += p;
      }
      #pragma unroll
      for (int off = 1; off < 16; off <<= 1) ps += __shfl_xor(ps, off);
      lsum[r] = lsum[r] * al + ps;
      #pragma unroll
      for (int d = 0; d < 4; ++d) po[d][r] *= al;
    }
    #pragma unroll
    for (int cb = 0; cb < 4; ++cb)
      #pragma unroll
      for (int r = 0; r < 4; ++r)
        Pl[w][(lg * 4 + r) * 72 + cb * 16 + lc] = f2bf(sacc[cb][r]);
    __syncthreads();
    bf16x8 pa0 = *(const bf16x8*)(&Pl[w][lc * 72 + lg * 8]);
    bf16x8 pa1 = *(const bf16x8*)(&Pl[w][lc * 72 + 32 + lg * 8]);
    #pragma unroll
    for (int d = 0; d < 4; ++d) {
      bf16x8 vb0 = *(const bf16x8*)(&Vt[(d * 16 + lc) * 72 + lg * 8]);
      bf16x8 vb1 = *(const bf16x8*)(&Vt[(d * 16 + lc) * 72 + 32 + lg * 8]);
      po[d] = __builtin_amdgcn_mfma_f32_16x16x32_bf16(pa0, vb0, po[d], 0, 0, 0);
      po[d] = __builtin_amdgcn_mfma_f32_16x16x32_bf16(pa1, vb1, po[d], 0, 0, 0);
    }
  }
  #pragma unroll
  for (int d = 0; d < 4; ++d)
    #pragma unroll
    for (int r = 0; r < 4; ++r) {
      int token = b * 1024 + qt * 64 + w * 16 + lg * 4 + r;
      float o = po[d][r] / lsum[r];
      hbuf[(size_t)token * HF + hh * HD + d * 16 + lc] = f2bf(o);
    }
}

// ---------------- GEMM2: out2 = h[perm] @ Wc^T + bias, masked; skip dead col-tiles ----
__global__ __launch_bounds__(256) void gemm2_kernel(const short* __restrict__ h,
                                                    const short* __restrict__ Wc,
                                                    const float* __restrict__ cbias,
                                                    const int* __restrict__ perm,
                                                    const int* __restrict__ dsrt,
                                                    const int* __restrict__ tmax,
                                                    short* __restrict__ out2) {
  __shared__ __align__(16) short AS[3 * ABUF];
  __shared__ __align__(16) short BS[3 * BBUF];
  f32x4 acc[4][2];
  f32x4 z = {0.f, 0.f, 0.f, 0.f};
  #pragma unroll
  for (int i = 0; i < 4; ++i)
    #pragma unroll
    for (int j = 0; j < 2; ++j) acc[i][j] = z;
  int bx, by;
  xcd_swizzle_cm(bx, by);
  int n0 = bx * 128;
  int m0 = by * 64;
  int demax = tmax[by];
  if ((n0 & (DIM - 1)) < demax)
    gemm_core_64(h, Wc, HF, HF, HF, m0, n0, perm, AS, BS, acc);
  const int tid = threadIdx.x, lane = tid & 63, wid = tid >> 6;
  const int lg = lane >> 4, lc = lane & 15;
  int toks[4][4], des[4][4];
  #pragma unroll
  for (int i = 0; i < 4; ++i)
    #pragma unroll
    for (int r = 0; r < 4; ++r) {
      int ms = m0 + i * 16 + lg * 4 + r;
      toks[i][r] = perm[ms];
      des[i][r] = dsrt[ms];
    }
  #pragma unroll
  for (int i = 0; i < 4; ++i) {
    #pragma unroll
    for (int j = 0; j < 2; ++j) {
      int o = n0 + wid * 32 + j * 16 + lc;
      float bias = cbias[o];
      #pragma unroll
      for (int r = 0; r < 4; ++r) {
        float val = acc[i][j][r] + bias;
        if ((o & (DIM - 1)) >= des[i][r]) val = 0.f;
        out2[(size_t)toks[i][r] * CON_N + o] = f2bf(val);
      }
    }
  }
}

// ---------------- final combine ----------------
__global__ __launch_bounds__(256) void combine_kernel(const float* __restrict__ x,
                                                      const float* __restrict__ probs,
                                                      const float* __restrict__ alpha,
                                                      const short* __restrict__ out2,
                                                      float* __restrict__ out) {
  int m = blockIdx.x, t = threadIdx.x;
  float coef = alpha[0] * probs[m] + 1.0f;
  f32x4 xv = *(const f32x4*)(&x[(size_t)m * DIM + t * 4]);
  s16x4 o1 = *(const s16x4*)(&out2[(size_t)m * CON_N + t * 4]);
  s16x4 o2 = *(const s16x4*)(&out2[(size_t)m * CON_N + DIM + t * 4]);
  f32x4 r;
  #pragma unroll
  for (int jj = 0; jj < 4; ++jj) r[jj] = xv[jj] + bf2f(o1[jj]) + coef * bf2f(o2[jj]);
  *(f32x4*)(&out[(size_t)m * DIM + t * 4]) = r;
}

extern "C" void kernel_launch(void* const* d_in, const int* in_sizes, int n_in,
                              void* d_out, int out_size, void* d_ws, size_t ws_size,
                              hipStream_t stream) {
  (void)in_sizes; (void)n_in; (void)out_size; (void)ws_size;
  const float* x     = (const float*)d_in[0];
  const int*   emask = (const int*)d_in[1];
  const float* probs = (const float*)d_in[2];
  const float* Wexp  = (const float*)d_in[3];
  const float* mlpb  = (const float*)d_in[4];
  const float* Wc    = (const float*)d_in[5];
  const float* cbias = (const float*)d_in[6];
  const float* n1g   = (const float*)d_in[7];
  const float* n1b   = (const float*)d_in[8];
  const float* n2g   = (const float*)d_in[9];
  const float* n2b   = (const float*)d_in[10];
  const float* alpha = (const float*)d_in[11];
  float* out = (float*)d_out;
  char* ws = (char*)d_ws;

  short* wexp_bf = (short*)(ws + WEXP_OFF);
  short* xn      = (short*)(ws + XN_OFF);
  short* wc_bf   = (short*)(ws + WC_OFF);
  short* qbuf    = (short*)(ws + Q_OFF);
  short* kbuf    = (short*)(ws + K_OFF);
  short* vbuf    = (short*)(ws + V_OFF);
  short* hbuf    = (short*)(ws + H_OFF);
  short* out2    = (short*)(ws + OUT2_OFF);
  int*   perm    = (int*)(ws + PERM_OFF);
  int*   dsrt    = (int*)(ws + DSRT_OFF);
  int*   tmaxb   = (int*)(ws + TMAX_OFF);

  hipLaunchKernelGGL(sort_kernel, dim3(1), dim3(256), 0, stream, emask, perm, dsrt, tmaxb);
  hipLaunchKernelGGL(f2bf_kernel, dim3(2048), dim3(256), 0, stream, Wexp, wexp_bf, (EXP_N * DIM) / 4);
  hipLaunchKernelGGL(ln1_kernel, dim3(TOKENS), dim3(256), 0, stream, x, emask, n1g, n1b, xn);
  hipLaunchKernelGGL(gemm1_kernel, dim3(EXP_N / 128, TOKENS / 64), dim3(256), 0, stream,
                     xn, wexp_bf, mlpb, perm, tmaxb, qbuf, kbuf, vbuf, hbuf);
  // Wc conversion MUST come after gemm1 (wc_bf aliases wexp_bf + xn)
  hipLaunchKernelGGL(f2bf_kernel, dim3(2048), dim3(256), 0, stream, Wc, wc_bf, (CON_N * HF) / 4);
  hipLaunchKernelGGL(ln2_kernel, dim3(2 * TOKENS), dim3(256), 0, stream, kbuf, vbuf, n2g, n2b);
  hipLaunchKernelGGL(attn_kernel, dim3(64, 16), dim3(256), 0, stream, qbuf, kbuf, vbuf, hbuf);
  hipLaunchKernelGGL(gemm2_kernel, dim3(CON_N / 128, TOKENS / 64), dim3(256), 0, stream,
                     hbuf, wc_bf, cbias, perm, dsrt, tmaxb, out2);
  hipLaunchKernelGGL(combine_kernel, dim3(TOKENS), dim3(256), 0, stream, x, probs, alpha, out2, out);
}

// Round 12
// 288.502 us; speedup vs baseline: 1.2935x; 1.2935x over previous
//
#include <hip/hip_runtime.h>
#include <hip/hip_bf16.h>

typedef __attribute__((ext_vector_type(8))) short bf16x8;
typedef __attribute__((ext_vector_type(4))) short s16x4;
typedef __attribute__((ext_vector_type(4))) float f32x4;

#define DIM    1024
#define TOKENS 4096
#define NHEAD  16
#define HD     64
#define EXP_N  7168
#define CON_N  2048
#define HF     5120

// workspace arena (bytes). NOTE liveness: wc_bf (WC_OFF=0) ALIASES
// wexp_bf + xn, so the Wc f2bf conversion MUST launch after gemm1.
#define WEXP_OFF 0u          // 7168*1024*2 = 14,680,064
#define XN_OFF   14680064u   // 4096*1024*2 =  8,388,608
#define WC_OFF   0u          // 2048*5120*2 = 20,971,520 (reuses Wexp+xn after gemm1)
#define Q_OFF    23068672u   // 8,388,608
#define K_OFF    31457280u   // 8,388,608
#define V_OFF    39845888u   // 8,388,608
#define H_OFF    48234496u   // 4096*5120*2 = 41,943,040
#define PERM_OFF 90177536u   // 4096*4
#define DSRT_OFF 90193920u   // 4096*4
#define TMAX_OFF 90210304u   // 32*4
#define VT_OFF   90210560u   // V^T [b][d][kv] 4096*1024*2 = 8,388,608 (end 98.6MB)
#define OUT2_OFF 23068672u   // 4096*2048*2 = 16,777,216 (reuses q+k after attn)

__device__ __forceinline__ short f2bf(float f) {
  union { __hip_bfloat16 h; short s; } u;
  u.h = __float2bfloat16(f);
  return u.s;
}
__device__ __forceinline__ float bf2f(short s) {
  unsigned int u = ((unsigned int)(unsigned short)s) << 16;
  return __builtin_bit_cast(float, u);
}

// async global -> LDS, 16 bytes per lane. LDS dest is wave-uniform base
// (HW writes lane i at base + i*16); global src address is PER-LANE.
__device__ __forceinline__ void gload16(const void* g, void* l) {
  __builtin_amdgcn_global_load_lds((const __attribute__((address_space(1))) void*)g,
                                   (__attribute__((address_space(3))) void*)l,
                                   16, 0, 0);
}

__device__ __forceinline__ void block_reduce_2(float& a, float& b) {
  #pragma unroll
  for (int off = 32; off > 0; off >>= 1) {
    a += __shfl_down(a, off);
    b += __shfl_down(b, off);
  }
  __shared__ float red[2][4];
  int wid = threadIdx.x >> 6, lane = threadIdx.x & 63;
  if (lane == 0) { red[0][wid] = a; red[1][wid] = b; }
  __syncthreads();
  a = red[0][0] + red[0][1] + red[0][2] + red[0][3];
  b = red[1][0] + red[1][1] + red[1][2] + red[1][3];
}

// ---------------- stable counting sort of tokens by expert id ----------------
// tile_demax[t] = max d_e over sorted rows [t*128, t*128+128)  (32 tiles)
__global__ __launch_bounds__(256) void sort_kernel(const int* __restrict__ emask,
                                                   int* __restrict__ perm,
                                                   int* __restrict__ de_sorted,
                                                   int* __restrict__ tile_demax) {
  __shared__ int cnt[4][256];
  __shared__ int boff[4];
  __shared__ int lm[256];
  const int t = threadIdx.x;
  const int lane = t & 63, w = t >> 6;
  int msk[16];
  int lc4[4] = {0, 0, 0, 0};
  #pragma unroll
  for (int j = 0; j < 16; ++j) { msk[j] = emask[t * 16 + j]; lc4[msk[j]]++; }
  #pragma unroll
  for (int b = 0; b < 4; ++b) cnt[b][t] = lc4[b];
  __syncthreads();
  {  // wave w: exclusive scan of bucket w over 256 thread-counts (4 per lane)
    int v0 = cnt[w][lane * 4], v1 = cnt[w][lane * 4 + 1];
    int v2 = cnt[w][lane * 4 + 2], v3 = cnt[w][lane * 4 + 3];
    int s = v0 + v1 + v2 + v3;
    int inc = s;
    #pragma unroll
    for (int off = 1; off < 64; off <<= 1) {
      int n = __shfl_up(inc, off);
      if (lane >= off) inc += n;
    }
    int ex = inc - s;
    cnt[w][lane * 4]     = ex;
    cnt[w][lane * 4 + 1] = ex + v0;
    cnt[w][lane * 4 + 2] = ex + v0 + v1;
    cnt[w][lane * 4 + 3] = ex + v0 + v1 + v2;
    if (lane == 63) boff[w] = inc;  // bucket total (temp)
  }
  __syncthreads();
  if (t == 0) {
    int t0 = boff[0], t1 = boff[1], t2 = boff[2];
    boff[0] = 0; boff[1] = t0; boff[2] = t0 + t1; boff[3] = t0 + t1 + t2;
  }
  __syncthreads();
  int c4[4] = {0, 0, 0, 0};
  #pragma unroll
  for (int j = 0; j < 16; ++j) {
    int b = msk[j];
    int pos = boff[b] + cnt[b][t] + c4[b]++;
    perm[pos] = t * 16 + j;
    de_sorted[pos] = DIM >> (3 - b);
  }
  __syncthreads();
  int mx = 0;
  #pragma unroll
  for (int j = 0; j < 16; ++j) mx = max(mx, de_sorted[t * 16 + j]);
  lm[t] = mx;
  __syncthreads();
  if (t < 32) {
    int m2 = 0;
    #pragma unroll
    for (int j = 0; j < 8; ++j) m2 = max(m2, lm[t * 8 + j]);
    tile_demax[t] = m2;
  }
}

// ---------------- fp32 -> bf16 weight conversion ----------------
__global__ __launch_bounds__(256) void f2bf_kernel(const float* __restrict__ in,
                                                   short* __restrict__ outp, int n4) {
  for (int i = blockIdx.x * blockDim.x + threadIdx.x; i < n4; i += gridDim.x * blockDim.x) {
    f32x4 xv = *(const f32x4*)(&in[(size_t)i * 4]);
    s16x4 o = { f2bf(xv[0]), f2bf(xv[1]), f2bf(xv[2]), f2bf(xv[3]) };
    *(s16x4*)(&outp[(size_t)i * 4]) = o;
  }
}

// ---------------- LN1 + fmask -> xn (bf16) ----------------
__global__ __launch_bounds__(256) void ln1_kernel(const float* __restrict__ x,
                                                  const int* __restrict__ emask,
                                                  const float* __restrict__ g,
                                                  const float* __restrict__ bb,
                                                  short* __restrict__ xn) {
  int m = blockIdx.x, t = threadIdx.x;
  const float* row = x + (size_t)m * DIM;
  f32x4 xv = *(const f32x4*)(&row[t * 4]);
  float s  = xv[0] + xv[1] + xv[2] + xv[3];
  float ss = xv[0] * xv[0] + xv[1] * xv[1] + xv[2] * xv[2] + xv[3] * xv[3];
  block_reduce_2(s, ss);
  float mean = s * (1.0f / DIM);
  float var  = ss * (1.0f / DIM) - mean * mean;
  float inv  = rsqrtf(var + 1e-5f);
  int de = DIM >> (3 - emask[m]);
  s16x4 o;
  #pragma unroll
  for (int jj = 0; jj < 4; ++jj) {
    int c = t * 4 + jj;
    float v = (c < de) ? ((xv[jj] - mean) * inv * g[c] + bb[c]) : 0.f;
    o[jj] = f2bf(v);
  }
  *(s16x4*)(&xn[(size_t)m * DIM + t * 4]) = o;
}

// ---------------- shared 128x128xK bf16 GEMM core, 512 threads / 8 waves ----
// (round-10 config: best measured). T2 swizzle (linear gload_lds dest +
// pre-swizzled global SOURCE unit (l&3)^((l>>3)&3) + swizzled READ unit
// lg^((lc>>1)&3)) -> SQ_LDS_BANK_CONFLICT == 0 (verified round 10).
// Pipeline: 3-buffer prefetch-distance-2, counted vmcnt 4/2/0 (T3+T4),
// setprio around MFMA (T5). K % 64 == 0, K >= 128.
#define GBUF 4096  // shorts per LDS buffer (128*32)

#define STAGE(Asb, Bsb, kk)                                   \
  do {                                                        \
    gload16(Apw + (kk), (Asb) + chw * 512);                   \
    gload16(Bpw + (kk), (Bsb) + chw * 512);                   \
  } while (0)

#define COMPUTE(Asb, Bsb)                                                     \
  do {                                                                        \
    bf16x8 af[4], bfr[2];                                                     \
    _Pragma("unroll")                                                         \
    for (int i = 0; i < 4; ++i)                                               \
      af[i] = *(const bf16x8*)(&(Asb)[(wr * 64 + i * 16 + lc) * 32 + lgs]);   \
    _Pragma("unroll")                                                         \
    for (int j = 0; j < 2; ++j)                                               \
      bfr[j] = *(const bf16x8*)(&(Bsb)[(wc * 32 + j * 16 + lc) * 32 + lgs]);  \
    __builtin_amdgcn_s_setprio(1);                                            \
    _Pragma("unroll")                                                         \
    for (int i = 0; i < 4; ++i)                                               \
      _Pragma("unroll")                                                       \
      for (int j = 0; j < 2; ++j)                                             \
        acc[i][j] = __builtin_amdgcn_mfma_f32_16x16x32_bf16(af[i], bfr[j],    \
                                                            acc[i][j], 0, 0, 0);\
    __builtin_amdgcn_s_setprio(0);                                            \
  } while (0)

#define VMCNT(n) asm volatile("s_waitcnt vmcnt(" #n ")" ::: "memory")

__device__ __forceinline__ void gemm_core_128(const short* __restrict__ A,
                                              const short* __restrict__ B,
                                              int lda, int ldb, int K,
                                              int m0, int n0,
                                              const int* __restrict__ aperm,
                                              short* AS, short* BS,
                                              f32x4 acc[4][2]) {
  const int tid = threadIdx.x;
  const int lane = tid & 63;
  const int wid = tid >> 6;           // 0..7
  const int wr = wid >> 2, wc = wid & 3;
  const int lg = lane >> 4, lc = lane & 15;
  const int lgs = (lg ^ ((lc >> 1) & 3)) * 8;   // swizzled read unit (shorts)
  const int r4 = lane >> 2;        // 0..15
  const int c8 = ((lane & 3) ^ ((lane >> 3) & 3)) * 8;  // swizzled src unit
  const int chw = wid;             // this wave's staging chunk
  int ra = m0 + chw * 16 + r4;
  if (aperm) ra = aperm[ra];
  const short* Apw = A + (size_t)ra * lda + c8;
  const short* Bpw = B + (size_t)(n0 + chw * 16 + r4) * ldb + c8;

  const int nt = K >> 5;           // 32-K steps, nt >= 4
  STAGE(AS + 0 * GBUF, BS + 0 * GBUF, 0);
  STAGE(AS + 1 * GBUF, BS + 1 * GBUF, 32);
  STAGE(AS + 2 * GBUF, BS + 2 * GBUF, 64);
  int cur = 0;
  for (int t = 0; t < nt - 2; ++t) {
    short* Ac = AS + cur * GBUF;
    short* Bc = BS + cur * GBUF;
    VMCNT(4);
    __builtin_amdgcn_s_barrier();
    COMPUTE(Ac, Bc);
    __builtin_amdgcn_s_barrier();
    if (t < nt - 3) STAGE(Ac, Bc, (t + 3) * 32);
    cur = (cur == 2) ? 0 : cur + 1;
  }
  {
    short* Ac = AS + cur * GBUF;
    short* Bc = BS + cur * GBUF;
    VMCNT(2);
    __builtin_amdgcn_s_barrier();
    COMPUTE(Ac, Bc);
    cur = (cur == 2) ? 0 : cur + 1;
  }
  {
    short* Ac = AS + cur * GBUF;
    short* Bc = BS + cur * GBUF;
    VMCNT(0);
    __builtin_amdgcn_s_barrier();
    COMPUTE(Ac, Bc);
  }
}

// XCD-aware bijective block swizzle, COLUMN-MAJOR decode.
__device__ __forceinline__ void xcd_swizzle_cm(int& bx, int& by) {
  int nwg = gridDim.x * gridDim.y;
  int bid = blockIdx.y * gridDim.x + blockIdx.x;
  int cpx = nwg >> 3;
  int swz = (bid & 7) * cpx + (bid >> 3);
  by = swz % gridDim.y;
  bx = swz / gridDim.y;
}

// ---------------- GEMM1: y = xn[perm] @ Wexp^T, K limited to tile d_e max ----
__global__ __launch_bounds__(512) void gemm1_kernel(const short* __restrict__ xn,
                                                    const short* __restrict__ Wexp,
                                                    const float* __restrict__ mlpb,
                                                    const int* __restrict__ perm,
                                                    const int* __restrict__ tmax,
                                                    short* __restrict__ qbuf,
                                                    short* __restrict__ kbuf,
                                                    short* __restrict__ vbuf,
                                                    short* __restrict__ hbuf) {
  __shared__ __align__(16) short AS[3 * GBUF];
  __shared__ __align__(16) short BS[3 * GBUF];
  f32x4 acc[4][2];
  f32x4 z = {0.f, 0.f, 0.f, 0.f};
  #pragma unroll
  for (int i = 0; i < 4; ++i)
    #pragma unroll
    for (int j = 0; j < 2; ++j) acc[i][j] = z;
  int bx, by;
  xcd_swizzle_cm(bx, by);
  int n0 = bx * 128;
  int m0 = by * 128;
  int kmax = tmax[by];
  gemm_core_128(xn, Wexp, DIM, DIM, kmax, m0, n0, perm, AS, BS, acc);
  const int tid = threadIdx.x, lane = tid & 63, wid = tid >> 6;
  const int wr = wid >> 2, wc = wid & 3, lg = lane >> 4, lc = lane & 15;
  int toks[4][4];
  #pragma unroll
  for (int i = 0; i < 4; ++i)
    #pragma unroll
    for (int r = 0; r < 4; ++r)
      toks[i][r] = perm[m0 + wr * 64 + i * 16 + lg * 4 + r];
  #pragma unroll
  for (int i = 0; i < 4; ++i) {
    #pragma unroll
    for (int j = 0; j < 2; ++j) {
      int e = n0 + wc * 32 + j * 16 + lc;
      #pragma unroll
      for (int r = 0; r < 4; ++r) {
        int m = toks[i][r];
        float val = acc[i][j][r];
        if (e < DIM) {
          qbuf[(size_t)m * DIM + e] = f2bf((val + mlpb[e]) * 0.125f);
        } else if (e < 2 * DIM) {
          kbuf[(size_t)m * DIM + (e - DIM)] = f2bf(val + mlpb[e]);
        } else if (e < 3 * DIM) {
          vbuf[(size_t)m * DIM + (e - 2 * DIM)] = f2bf(val + mlpb[e]);
        } else {
          int jj = e - 3 * DIM;
          float xx = val + mlpb[jj] + (e < 4 * DIM ? mlpb[e] : 0.f);
          float ge = 0.5f * xx * (1.f + erff(xx * 0.70710678118654752f));
          hbuf[(size_t)m * HF + DIM + jj] = f2bf(ge);
        }
      }
    }
  }
}

// ---------------- LN2 in place on k/v (bf16 rows) ----------------
__global__ __launch_bounds__(256) void ln2_kernel(short* __restrict__ kbuf,
                                                  short* __restrict__ vbuf,
                                                  const float* __restrict__ g,
                                                  const float* __restrict__ bb) {
  int rr = blockIdx.x;
  int m = rr >> 1;
  short* row = ((rr & 1) ? vbuf : kbuf) + (size_t)m * DIM;
  int t = threadIdx.x;
  s16x4 iv = *(const s16x4*)(&row[t * 4]);
  float f[4];
  #pragma unroll
  for (int jj = 0; jj < 4; ++jj) f[jj] = bf2f(iv[jj]);
  float s = f[0] + f[1] + f[2] + f[3];
  float ss = f[0] * f[0] + f[1] * f[1] + f[2] * f[2] + f[3] * f[3];
  block_reduce_2(s, ss);
  float mean = s * (1.0f / DIM);
  float var  = ss * (1.0f / DIM) - mean * mean;
  float inv  = rsqrtf(var + 1e-5f);
  s16x4 o;
  #pragma unroll
  for (int jj = 0; jj < 4; ++jj) {
    int c = t * 4 + jj;
    o[jj] = f2bf((f[jj] - mean) * inv * g[c] + bb[c]);
  }
  *(s16x4*)(&row[t * 4]) = o;
}

// ---------------- V -> V^T tiled transpose (post-LN2) ----------------
// vt[b][d][kv] = v[b*1024 + kv][d]. 64x64 tiles, LDS stride 72.
__global__ __launch_bounds__(256) void vtrans_kernel(const short* __restrict__ v,
                                                     short* __restrict__ vt) {
  __shared__ short tl[64][72];
  const int bidx = blockIdx.x;           // b(2) x dt(4) x kt(4)
  const int kt = bidx & 15, dt = (bidx >> 4) & 15, b = bidx >> 8;
  const int tid = threadIdx.x;
  const int row = tid >> 3, c8 = (tid & 7) * 8;
  #pragma unroll
  for (int it = 0; it < 2; ++it) {
    int r = row + it * 32;               // kv-local
    *(bf16x8*)(&tl[r][c8]) =
      *(const bf16x8*)(&v[((size_t)(b * 1024 + kt * 64 + r)) * DIM + dt * 64 + c8]);
  }
  __syncthreads();
  #pragma unroll
  for (int it = 0; it < 2; ++it) {
    int d = row + it * 32;               // d-local
    bf16x8 o;
    #pragma unroll
    for (int jj = 0; jj < 8; ++jj) o[jj] = tl[c8 + jj][d];
    *(bf16x8*)(&vt[((size_t)(b * 1024 + dt * 64 + d)) * 1024 + kt * 64 + c8]) = o;
  }
}

// ---------------- flash attention: per (b,h) 64 q-rows per block ----------------
// V consumed from pre-transposed vt (coalesced b128 staging, conflict-free);
// Pl is per-warp -> no barrier between its write and read.
__global__ __launch_bounds__(256) void attn_kernel(const short* __restrict__ q,
                                                   const short* __restrict__ k,
                                                   const short* __restrict__ vt,
                                                   short* __restrict__ hbuf) {
  __shared__ __align__(16) short Kt[64 * 72];
  __shared__ __align__(16) short Vt[64 * 72];
  __shared__ __align__(16) short Pl[4][16 * 72];
  const int bh = blockIdx.x;
  const int b = bh >> 4, hh = bh & 15;
  const int qt = blockIdx.y;
  const int tid = threadIdx.x, w = tid >> 6, lane = tid & 63;
  const int lg = lane >> 4, lc = lane & 15;

  bf16x8 qa0, qa1;
  {
    const short* qbase = q + ((size_t)(b * 1024 + qt * 64 + w * 16 + lc)) * DIM + hh * HD;
    qa0 = *(const bf16x8*)(qbase + lg * 8);
    qa1 = *(const bf16x8*)(qbase + 32 + lg * 8);
  }
  f32x4 po[4];
  f32x4 z = {0.f, 0.f, 0.f, 0.f};
  #pragma unroll
  for (int d = 0; d < 4; ++d) po[d] = z;
  float mrun[4] = {-INFINITY, -INFINITY, -INFINITY, -INFINITY};
  float lsum[4] = {0.f, 0.f, 0.f, 0.f};

  for (int kt = 0; kt < 16; ++kt) {
    __syncthreads();
    const int kc0 = kt * 64;
    #pragma unroll
    for (int it = 0; it < 2; ++it) {
      int row = (tid >> 3) + it * 32;
      int c8 = (tid & 7) * 8;
      // K tile: rows = kv, cols = hd
      size_t gk = ((size_t)(b * 1024 + kc0 + row)) * DIM + hh * HD + c8;
      *(bf16x8*)(&Kt[row * 72 + c8]) = *(const bf16x8*)(&k[gk]);
      // V^T tile: rows = hd, cols = kv (from pre-transposed vt)
      size_t gv = ((size_t)(b * 1024 + hh * HD + row)) * 1024 + kc0 + c8;
      *(bf16x8*)(&Vt[row * 72 + c8]) = *(const bf16x8*)(&vt[gv]);
    }
    __syncthreads();
    f32x4 sacc[4];
    #pragma unroll
    for (int cb = 0; cb < 4; ++cb) {
      bf16x8 kb0 = *(const bf16x8*)(&Kt[(cb * 16 + lc) * 72 + lg * 8]);
      bf16x8 kb1 = *(const bf16x8*)(&Kt[(cb * 16 + lc) * 72 + 32 + lg * 8]);
      f32x4 t0 = __builtin_amdgcn_mfma_f32_16x16x32_bf16(qa0, kb0, z, 0, 0, 0);
      sacc[cb] = __builtin_amdgcn_mfma_f32_16x16x32_bf16(qa1, kb1, t0, 0, 0, 0);
    }
    #pragma unroll
    for (int r = 0; r < 4; ++r) {
      float mx = fmaxf(fmaxf(sacc[0][r], sacc[1][r]), fmaxf(sacc[2][r], sacc[3][r]));
      #pragma unroll
      for (int off = 1; off < 16; off <<= 1) mx = fmaxf(mx, __shfl_xor(mx, off));
      float mnew = fmaxf(mrun[r], mx);
      float al = __expf(mrun[r] - mnew);
      mrun[r] = mnew;
      float ps = 0.f;
      #pragma unroll
      for (int cb = 0; cb < 4; ++cb) {
        float p = __expf(sacc[cb][r] - mnew);
        sacc[cb][r] = p;
        ps += p;
      }
      #pragma unroll
      for (int off = 1; off < 16; off <<= 1) ps += __shfl_xor(ps, off);
      lsum[r] = lsum[r] * al + ps;
      #pragma unroll
      for (int d = 0; d < 4; ++d) po[d][r] *= al;
    }
    #pragma unroll
    for (int cb = 0; cb < 4; ++cb)
      #pragma unroll
      for (int r = 0; r < 4; ++r)
        Pl[w][(lg * 4 + r) * 72 + cb * 16 + lc] = f2bf(sacc[cb][r]);
    // NOTE: no barrier — Pl[w] is written and read by warp w only;
    // compiler inserts the lgkmcnt for the same-wave RAW.
    bf16x8 pa0 = *(const bf16x8*)(&Pl[w][lc * 72 + lg * 8]);
    bf16x8 pa1 = *(const bf16x8*)(&Pl[w][lc * 72 + 32 + lg * 8]);
    #pragma unroll
    for (int d = 0; d < 4; ++d) {
      bf16x8 vb0 = *(const bf16x8*)(&Vt[(d * 16 + lc) * 72 + lg * 8]);
      bf16x8 vb1 = *(const bf16x8*)(&Vt[(d * 16 + lc) * 72 + 32 + lg * 8]);
      po[d] = __builtin_amdgcn_mfma_f32_16x16x32_bf16(pa0, vb0, po[d], 0, 0, 0);
      po[d] = __builtin_amdgcn_mfma_f32_16x16x32_bf16(pa1, vb1, po[d], 0, 0, 0);
    }
  }
  #pragma unroll
  for (int d = 0; d < 4; ++d)
    #pragma unroll
    for (int r = 0; r < 4; ++r) {
      int token = b * 1024 + qt * 64 + w * 16 + lg * 4 + r;
      float o = po[d][r] / lsum[r];
      hbuf[(size_t)token * HF + hh * HD + d * 16 + lc] = f2bf(o);
    }
}

// ---------------- GEMM2: out2 = h[perm] @ Wc^T + bias, masked; skip dead col-tiles ----
__global__ __launch_bounds__(512) void gemm2_kernel(const short* __restrict__ h,
                                                    const short* __restrict__ Wc,
                                                    const float* __restrict__ cbias,
                                                    const int* __restrict__ perm,
                                                    const int* __restrict__ dsrt,
                                                    const int* __restrict__ tmax,
                                                    short* __restrict__ out2) {
  __shared__ __align__(16) short AS[3 * GBUF];
  __shared__ __align__(16) short BS[3 * GBUF];
  f32x4 acc[4][2];
  f32x4 z = {0.f, 0.f, 0.f, 0.f};
  #pragma unroll
  for (int i = 0; i < 4; ++i)
    #pragma unroll
    for (int j = 0; j < 2; ++j) acc[i][j] = z;
  int bx, by;
  xcd_swizzle_cm(bx, by);
  int n0 = bx * 128;
  int m0 = by * 128;
  int demax = tmax[by];
  if ((n0 & (DIM - 1)) < demax)
    gemm_core_128(h, Wc, HF, HF, HF, m0, n0, perm, AS, BS, acc);
  const int tid = threadIdx.x, lane = tid & 63, wid = tid >> 6;
  const int wr = wid >> 2, wc = wid & 3, lg = lane >> 4, lc = lane & 15;
  int toks[4][4], des[4][4];
  #pragma unroll
  for (int i = 0; i < 4; ++i)
    #pragma unroll
    for (int r = 0; r < 4; ++r) {
      int ms = m0 + wr * 64 + i * 16 + lg * 4 + r;
      toks[i][r] = perm[ms];
      des[i][r] = dsrt[ms];
    }
  #pragma unroll
  for (int i = 0; i < 4; ++i) {
    #pragma unroll
    for (int j = 0; j < 2; ++j) {
      int o = n0 + wc * 32 + j * 16 + lc;
      float bias = cbias[o];
      #pragma unroll
      for (int r = 0; r < 4; ++r) {
        float val = acc[i][j][r] + bias;
        if ((o & (DIM - 1)) >= des[i][r]) val = 0.f;
        out2[(size_t)toks[i][r] * CON_N + o] = f2bf(val);
      }
    }
  }
}

// ---------------- final combine ----------------
__global__ __launch_bounds__(256) void combine_kernel(const float* __restrict__ x,
                                                      const float* __restrict__ probs,
                                                      const float* __restrict__ alpha,
                                                      const short* __restrict__ out2,
                                                      float* __restrict__ out) {
  int m = blockIdx.x, t = threadIdx.x;
  float coef = alpha[0] * probs[m] + 1.0f;
  f32x4 xv = *(const f32x4*)(&x[(size_t)m * DIM + t * 4]);
  s16x4 o1 = *(const s16x4*)(&out2[(size_t)m * CON_N + t * 4]);
  s16x4 o2 = *(const s16x4*)(&out2[(size_t)m * CON_N + DIM + t * 4]);
  f32x4 r;
  #pragma unroll
  for (int jj = 0; jj < 4; ++jj) r[jj] = xv[jj] + bf2f(o1[jj]) + coef * bf2f(o2[jj]);
  *(f32x4*)(&out[(size_t)m * DIM + t * 4]) = r;
}

extern "C" void kernel_launch(void* const* d_in, const int* in_sizes, int n_in,
                              void* d_out, int out_size, void* d_ws, size_t ws_size,
                              hipStream_t stream) {
  (void)in_sizes; (void)n_in; (void)out_size; (void)ws_size;
  const float* x     = (const float*)d_in[0];
  const int*   emask = (const int*)d_in[1];
  const float* probs = (const float*)d_in[2];
  const float* Wexp  = (const float*)d_in[3];
  const float* mlpb  = (const float*)d_in[4];
  const float* Wc    = (const float*)d_in[5];
  const float* cbias = (const float*)d_in[6];
  const float* n1g   = (const float*)d_in[7];
  const float* n1b   = (const float*)d_in[8];
  const float* n2g   = (const float*)d_in[9];
  const float* n2b   = (const float*)d_in[10];
  const float* alpha = (const float*)d_in[11];
  float* out = (float*)d_out;
  char* ws = (char*)d_ws;

  short* wexp_bf = (short*)(ws + WEXP_OFF);
  short* xn      = (short*)(ws + XN_OFF);
  short* wc_bf   = (short*)(ws + WC_OFF);
  short* qbuf    = (short*)(ws + Q_OFF);
  short* kbuf    = (short*)(ws + K_OFF);
  short* vbuf    = (short*)(ws + V_OFF);
  short* hbuf    = (short*)(ws + H_OFF);
  short* vtbuf   = (short*)(ws + VT_OFF);
  short* out2    = (short*)(ws + OUT2_OFF);
  int*   perm    = (int*)(ws + PERM_OFF);
  int*   dsrt    = (int*)(ws + DSRT_OFF);
  int*   tmaxb   = (int*)(ws + TMAX_OFF);

  hipLaunchKernelGGL(sort_kernel, dim3(1), dim3(256), 0, stream, emask, perm, dsrt, tmaxb);
  hipLaunchKernelGGL(f2bf_kernel, dim3(2048), dim3(256), 0, stream, Wexp, wexp_bf, (EXP_N * DIM) / 4);
  hipLaunchKernelGGL(ln1_kernel, dim3(TOKENS), dim3(256), 0, stream, x, emask, n1g, n1b, xn);
  hipLaunchKernelGGL(gemm1_kernel, dim3(EXP_N / 128, TOKENS / 128), dim3(512), 0, stream,
                     xn, wexp_bf, mlpb, perm, tmaxb, qbuf, kbuf, vbuf, hbuf);
  // Wc conversion MUST come after gemm1 (wc_bf aliases wexp_bf + xn)
  hipLaunchKernelGGL(f2bf_kernel, dim3(2048), dim3(256), 0, stream, Wc, wc_bf, (CON_N * HF) / 4);
  hipLaunchKernelGGL(ln2_kernel, dim3(2 * TOKENS), dim3(256), 0, stream, kbuf, vbuf, n2g, n2b);
  hipLaunchKernelGGL(vtrans_kernel, dim3(1024), dim3(256), 0, stream, vbuf, vtbuf);
  hipLaunchKernelGGL(attn_kernel, dim3(64, 16), dim3(256), 0, stream, qbuf, kbuf, vtbuf, hbuf);
  hipLaunchKernelGGL(gemm2_kernel, dim3(CON_N / 128, TOKENS / 128), dim3(512), 0, stream,
                     hbuf, wc_bf, cbias, perm, dsrt, tmaxb, out2);
  hipLaunchKernelGGL(combine_kernel, dim3(TOKENS), dim3(256), 0, stream, x, probs, alpha, out2, out);
}